// Round 18
// baseline (264.901 us; speedup 1.0000x reference)
//
#include <hip/hip_runtime.h>
#include <math.h>

// Problem constants
constexpr int T_ = 1024, S_ = 1024, B_ = 4, E_ = 1024, H_ = 16, D_ = 64;
constexpr float SCALE_ = 0.125f;                  // D^-0.5
constexpr size_t NH_ = (size_t)B_ * H_ * T_ * D_; // 4,194,304 elems
constexpr size_t EE_ = (size_t)E_ * E_;           // 1,048,576 elems

typedef _Float16 h8 __attribute__((ext_vector_type(8)));
typedef _Float16 h4 __attribute__((ext_vector_type(4)));
typedef float f4 __attribute__((ext_vector_type(4)));

__device__ inline f4 mfma16(h8 a, h8 b, f4 c) {
    return __builtin_amdgcn_mfma_f32_16x16x32_f16(a, b, c, 0, 0, 0);
}

// async global->LDS, 16B per lane; lds dest = wave-uniform base + lane*16
__device__ inline void gload_lds16(const void* g, void* l) {
    __builtin_amdgcn_global_load_lds(
        (const __attribute__((address_space(1))) void*)g,
        (__attribute__((address_space(3))) void*)l, 16, 0, 0);
}

// ---------------------------------------------------------------------------
// Fused f32 -> f16 converter for all 7 tensors (outputs contiguous in ws).
// ---------------------------------------------------------------------------
__global__ __launch_bounds__(256) void cvt_all(
    const float* __restrict__ q, const float* __restrict__ k,
    const float* __restrict__ v, const float* __restrict__ wq,
    const float* __restrict__ wk, const float* __restrict__ wv,
    const float* __restrict__ wp, _Float16* __restrict__ dst)
{
    const int i8 = blockIdx.x * 256 + threadIdx.x;   // 0 .. 2097151
    constexpr int BIG = (int)(NH_ / 8);              // 524288
    constexpr int WSZ = (int)(EE_ / 8);              // 131072
    const float* src;
    int loc;
    if (i8 < 3 * BIG) {
        int t = i8 / BIG; loc = i8 - t * BIG;
        src = t == 0 ? q : (t == 1 ? k : v);
    } else {
        int r = i8 - 3 * BIG;
        int t = r / WSZ; loc = r - t * WSZ;
        src = t == 0 ? wq : (t == 1 ? wk : (t == 2 ? wv : wp));
    }
    const float* p = src + (size_t)loc * 8;
    float4 a = *(const float4*)p;
    float4 b = *(const float4*)(p + 4);
    h8 o;
    o[0] = (_Float16)a.x; o[1] = (_Float16)a.y;
    o[2] = (_Float16)a.z; o[3] = (_Float16)a.w;
    o[4] = (_Float16)b.x; o[5] = (_Float16)b.y;
    o[6] = (_Float16)b.z; o[7] = (_Float16)b.w;
    *(h8*)&dst[(size_t)i8 * 8] = o;
}

// ---------------------------------------------------------------------------
// GEMM core 64x128 (out_gemm): BK=64, 512 thr = 8 waves (2x4), wave 32x32.
// ---------------------------------------------------------------------------
template <typename EPI>
__device__ inline void gemm_core(
    const _Float16* __restrict__ A, const _Float16* __restrict__ W,
    int m0, int n0, EPI epi)
{
    __shared__ _Float16 As[64][64];    //  8 KB linear
    __shared__ _Float16 Bs[128][64];   // 16 KB linear

    const int tid = threadIdx.x;
    const int w = tid >> 6, l = tid & 63, lr = l & 15, lg = l >> 4;
    const int wr = w >> 2, wc = w & 3;

    const int srow = (w << 3) + (l >> 3);       // 0..63 staged row
    const int sg   = (l & 7) ^ (srow & 7);      // swizzled source chunk
    char* AsB = (char*)As;
    char* BsB = (char*)Bs;
    char* ldsA  = AsB + w * 1024;
    char* ldsB0 = BsB + w * 1024;
    char* ldsB1 = BsB + 8192 + w * 1024;

    f4 acc[2][2];
#pragma unroll
    for (int mi = 0; mi < 2; ++mi)
#pragma unroll
        for (int ni = 0; ni < 2; ++ni) acc[mi][ni] = (f4){0.f, 0.f, 0.f, 0.f};

    for (int k0 = 0; k0 < 1024; k0 += 64) {
        gload_lds16(&A[(size_t)(m0 + srow) * 1024 + k0 + sg * 8], ldsA);
        gload_lds16(&W[(size_t)(n0 + srow) * 1024 + k0 + sg * 8], ldsB0);
        gload_lds16(&W[(size_t)(n0 + 64 + srow) * 1024 + k0 + sg * 8], ldsB1);
        __syncthreads();
#pragma unroll
        for (int kk = 0; kk < 2; ++kk) {
            h8 af[2], bf[2];
#pragma unroll
            for (int mi = 0; mi < 2; ++mi) {
                int r = wr * 32 + mi * 16 + lr, kc = kk * 4 + lg;
                af[mi] = *(const h8*)(AsB + r * 128 + ((kc ^ (r & 7)) << 4));
            }
#pragma unroll
            for (int ni = 0; ni < 2; ++ni) {
                int r = wc * 32 + ni * 16 + lr, kc = kk * 4 + lg;
                bf[ni] = *(const h8*)(BsB + r * 128 + ((kc ^ (r & 7)) << 4));
            }
#pragma unroll
            for (int mi = 0; mi < 2; ++mi)
#pragma unroll
                for (int ni = 0; ni < 2; ++ni)
                    acc[mi][ni] = mfma16(af[mi], bf[ni], acc[mi][ni]);
        }
        __syncthreads();
    }

#pragma unroll
    for (int mi = 0; mi < 2; ++mi)
#pragma unroll
        for (int ni = 0; ni < 2; ++ni)
#pragma unroll
            for (int r = 0; r < 4; ++r) {
                int row = m0 + wr * 32 + mi * 16 + lg * 4 + r;
                int col = n0 + wc * 32 + ni * 16 + lr;
                epi(row, col, acc[mi][ni][r]);
            }
}

// ---------------------------------------------------------------------------
// GEMM core 128x128 (qkv): BK=64, 512 thr = 8 waves (2x4), wave tile 64x32.
// ---------------------------------------------------------------------------
template <typename EPI>
__device__ inline void gemm_core128(
    const _Float16* __restrict__ A, const _Float16* __restrict__ W,
    int m0, int n0, EPI epi)
{
    __shared__ _Float16 As[128][64];   // 16 KB linear
    __shared__ _Float16 Bs[128][64];   // 16 KB linear

    const int tid = threadIdx.x;
    const int w = tid >> 6, l = tid & 63, lr = l & 15, lg = l >> 4;
    const int wr = w >> 2, wc = w & 3;

    char* AsB = (char*)As;
    char* BsB = (char*)Bs;

    f4 acc[4][2];
#pragma unroll
    for (int mi = 0; mi < 4; ++mi)
#pragma unroll
        for (int ni = 0; ni < 2; ++ni) acc[mi][ni] = (f4){0.f, 0.f, 0.f, 0.f};

    for (int k0 = 0; k0 < 1024; k0 += 64) {
#pragma unroll
        for (int d = 0; d < 2; ++d) {
            int row = w * 16 + d * 8 + (l >> 3);
            int sg = (l & 7) ^ (row & 7);
            gload_lds16(&A[(size_t)(m0 + row) * 1024 + k0 + sg * 8],
                        AsB + (w * 16 + d * 8) * 128);
            gload_lds16(&W[(size_t)(n0 + row) * 1024 + k0 + sg * 8],
                        BsB + (w * 16 + d * 8) * 128);
        }
        __syncthreads();
#pragma unroll
        for (int kk = 0; kk < 2; ++kk) {
            h8 af[4], bf[2];
#pragma unroll
            for (int mi = 0; mi < 4; ++mi) {
                int r = wr * 64 + mi * 16 + lr, kc = kk * 4 + lg;
                af[mi] = *(const h8*)(AsB + r * 128 + ((kc ^ (r & 7)) << 4));
            }
#pragma unroll
            for (int ni = 0; ni < 2; ++ni) {
                int r = wc * 32 + ni * 16 + lr, kc = kk * 4 + lg;
                bf[ni] = *(const h8*)(BsB + r * 128 + ((kc ^ (r & 7)) << 4));
            }
#pragma unroll
            for (int mi = 0; mi < 4; ++mi)
#pragma unroll
                for (int ni = 0; ni < 2; ++ni)
                    acc[mi][ni] = mfma16(af[mi], bf[ni], acc[mi][ni]);
        }
        __syncthreads();
    }

#pragma unroll
    for (int mi = 0; mi < 4; ++mi)
#pragma unroll
        for (int ni = 0; ni < 2; ++ni)
#pragma unroll
            for (int r = 0; r < 4; ++r) {
                int row = m0 + wr * 64 + mi * 16 + lg * 4 + r;
                int col = n0 + wc * 32 + ni * 16 + lr;
                epi(row, col, acc[mi][ni][r]);
            }
}

// ---------------------------------------------------------------------------
// Merged Q/K/V projection: blockIdx.z selects tensor. 128x128 tiles.
// ---------------------------------------------------------------------------
__global__ __launch_bounds__(512) void qkv_gemm(
    const _Float16* __restrict__ q16, const _Float16* __restrict__ k16,
    const _Float16* __restrict__ v16, const _Float16* __restrict__ Wq16,
    const _Float16* __restrict__ Wk16, const _Float16* __restrict__ Wv16,
    _Float16* __restrict__ qh, _Float16* __restrict__ kh,
    _Float16* __restrict__ vhT)
{
    const int z = blockIdx.z;
    const _Float16* A = z == 0 ? q16 : (z == 1 ? k16 : v16);
    const _Float16* W = z == 0 ? Wq16 : (z == 1 ? Wk16 : Wv16);
    _Float16* C = z == 0 ? qh : (z == 1 ? kh : vhT);
    const float scale = (z == 0) ? SCALE_ : 1.0f;
    const int m0 = blockIdx.x * 128, n0 = blockIdx.y * 128;

    if (z < 2) {
        gemm_core128(A, W, m0, n0, [&](int row, int col, float vv) {
            int t = row >> 2, b = row & 3, h = col >> 6, d = col & 63;
            C[(((size_t)b * H_ + h) * T_ + t) * D_ + d] = (_Float16)(vv * scale);
        });
    } else {
        gemm_core128(A, W, m0, n0, [&](int row, int col, float vv) {
            int s = row >> 2, b = row & 3, h = col >> 6, d = col & 63;
            C[(((size_t)b * H_ + h) * D_ + d) * S_ + s] = (_Float16)vv;
        });
    }
}

// ---------------------------------------------------------------------------
// Output projection: out = oh @ Wp^T + bp  (f32 out). 64x128 tiles.
// ---------------------------------------------------------------------------
__global__ __launch_bounds__(512) void out_gemm(
    const _Float16* __restrict__ oh, const _Float16* __restrict__ Wp16,
    const float* __restrict__ bp, float* __restrict__ out)
{
    const int m0 = blockIdx.x * 64, n0 = blockIdx.y * 128;
    gemm_core(oh, Wp16, m0, n0, [&](int row, int col, float vv) {
        out[(size_t)row * E_ + col] = vv + bp[col];
    });
}

// ---------------------------------------------------------------------------
// Fused attention (Round-10 structure; single change vs R17: ph2 attn stores
// are PLAIN (L2-buffered) instead of nontemporal, so the compiler's
// vmcnt(0)-at-barrier after ph2 completes at L2 (~200cy) instead of waiting
// for HBM (~900cy). R12 verified this layout's plain stores produce the same
// clean 270MB WRITE_SIZE.
// ---------------------------------------------------------------------------
__global__ __launch_bounds__(512, 6) void fused_attn(
    const _Float16* __restrict__ qh, const _Float16* __restrict__ kh,
    const _Float16* __restrict__ vhT, const float* __restrict__ bias,
    const int* __restrict__ mask, float* __restrict__ attn,
    _Float16* __restrict__ oh)
{
    __shared__ _Float16 Pf[16 * 1024];   // swizzled, 32 KB
    __shared__ int aux_i[1024];          // mask (ph1) / PV partials (ph3)
    __shared__ float wsum[8][16];
    __shared__ float sinv16[16];
    char* Pb = (char*)Pf;

    const int bid = blockIdx.x;
    const int vid = (bid & 7) * 512 + (bid >> 3);   // 4096 % 8 == 0, bijective
    const int bh = vid >> 6;              // 0..63
    const int t0 = (vid & 63) * 16;       // 0..1008
    const int b = bh >> 4, h = bh & 15;
    const int tid = threadIdx.x;
    const int w = tid >> 6, l = tid & 63, lr = l & 15, lg = l >> 4;

    // ---- early issue: bias tiles (lane l: t=l>>2, s-quad=l&3) + Q frags ----
    const float* bbase = bias + ((size_t)bh * T_ + t0) * S_;
    const int brow_ = l >> 2, bq_ = l & 3;
    f4 bv[8];
#pragma unroll
    for (int j = 0; j < 8; ++j)
        bv[j] = *(const f4*)&bbase[(size_t)brow_ * S_ + w * 128 + j * 16 + bq_ * 4];

    const _Float16* qbase = qh + ((size_t)bh * T_ + t0) * D_;
    h8 qf0 = *(const h8*)&qbase[(size_t)lr * D_ + lg * 8];
    h8 qf1 = *(const h8*)&qbase[(size_t)lr * D_ + 32 + lg * 8];
    __builtin_amdgcn_sched_barrier(0);    // pin early issue

    for (int i = tid; i < S_; i += 512) aux_i[i] = mask[(size_t)b * S_ + i];
    __syncthreads();                      // mask staged

    const _Float16* kbase = kh + (size_t)bh * S_ * D_;
    const int wbase = w * 128;            // this wave's s-stripe
    const int srcLane = lr * 4 + lg;      // bias^T shuffle source

    // ---- phase 1: P = mask?0:exp(S+bias^T) -> LDS; rowsum in regs ----
    float rs = 0.f;
#pragma unroll
    for (int sub = 0; sub < 8; ++sub) {
        int s0 = wbase + sub * 16;
        h8 kf0 = *(const h8*)&kbase[(size_t)(s0 + lr) * D_ + lg * 8];
        h8 kf1 = *(const h8*)&kbase[(size_t)(s0 + lr) * D_ + 32 + lg * 8];
        f4 c = (f4){0.f, 0.f, 0.f, 0.f};
        c = mfma16(kf0, qf0, c);
        c = mfma16(kf1, qf1, c);
        float b0 = __shfl(bv[sub][0], srcLane);
        float b1 = __shfl(bv[sub][1], srcLane);
        float b2 = __shfl(bv[sub][2], srcLane);
        float b3 = __shfl(bv[sub][3], srcLane);
        int4 mv = *(const int4*)&aux_i[s0 + lg * 4];
        float p0 = mv.x ? 0.f : __expf(c[0] + b0);
        float p1 = mv.y ? 0.f : __expf(c[1] + b1);
        float p2 = mv.z ? 0.f : __expf(c[2] + b2);
        float p3 = mv.w ? 0.f : __expf(c[3] + b3);
        rs += (p0 + p1) + (p2 + p3);
        h4 pv;
        pv[0] = (_Float16)p0; pv[1] = (_Float16)p1;
        pv[2] = (_Float16)p2; pv[3] = (_Float16)p3;
        int off = (lr * 2048 + (s0 + lg * 4) * 2) ^ ((lr & 7) << 4);
        *(h4*)(Pb + off) = pv;
    }
    // wave rowsum for t=lr: sum the 4 lg groups
    rs += __shfl_xor(rs, 16); rs += __shfl_xor(rs, 32);
    if (l < 16) wsum[w][lr] = rs;
    __syncthreads();

    // ---- phase 2: inv; attn = P*inv (PLAIN stores, 4 rows x 512B/instr) ----
    {
        const int rr2 = tid >> 5;         // 0..15
        const int c2  = tid & 31;         // 0..31
        float s8 = 0.f;
#pragma unroll
        for (int ww = 0; ww < 8; ++ww) s8 += wsum[ww][rr2];   // broadcast reads
        float inv = 1.0f / s8;
        if (c2 == 0) sinv16[rr2] = inv;   // consumed in ph3 after its barrier
        float* arow = attn + ((size_t)bh * T_ + t0 + rr2) * S_;
#pragma unroll
        for (int j = 0; j < 8; ++j) {
            int col = c2 * 4 + j * 128;
            int off = (rr2 * 2048 + col * 2) ^ ((rr2 & 7) << 4);
            h4 p = *(const h4*)(Pb + off);
            f4 o = {(float)p[0] * inv, (float)p[1] * inv,
                    (float)p[2] * inv, (float)p[3] * inv};
            *(f4*)&arow[col] = o;         // plain store (vs NT in R17)
        }
    }

    // ---- phase 3: PV, wave pairs split S (512 each), LDS reduce ----
    {
        const int sh = w & 1, dbase = (w >> 1) * 16;
        const _Float16* vbase = vhT + (size_t)bh * D_ * S_;
        f4 acc = (f4){0.f, 0.f, 0.f, 0.f};
#pragma unroll 8
        for (int kc = 0; kc < 16; ++kc) {
            int s0 = sh * 512 + kc * 32;
            int off = (lr * 2048 + (s0 + lg * 8) * 2) ^ ((lr & 7) << 4);
            h8 pf = *(const h8*)(Pb + off);
            h8 vf = *(const h8*)&vbase[(size_t)(dbase + lr) * S_ + s0 + lg * 8];
            acc = mfma16(pf, vf, acc);
        }
        float* pvred = (float*)aux_i;     // mask no longer needed
        if (sh) {
#pragma unroll
            for (int r = 0; r < 4; ++r)
                pvred[(lg * 4 + r) * 64 + dbase + lr] = acc[r];
        }
        __syncthreads();
        if (!sh) {
#pragma unroll
            for (int r = 0; r < 4; ++r) {
                int t = lg * 4 + r;
                float o = (acc[r] + pvred[t * 64 + dbase + lr]) * sinv16[t];
                oh[((size_t)(t0 + t) * B_ + b) * E_ + h * 64 + dbase + lr] = (_Float16)o;
            }
        }
    }
}

// ---------------------------------------------------------------------------
extern "C" void kernel_launch(void* const* d_in, const int* in_sizes, int n_in,
                              void* d_out, int out_size, void* d_ws, size_t ws_size,
                              hipStream_t stream)
{
    const float* q    = (const float*)d_in[0];
    const float* k    = (const float*)d_in[1];
    const float* v    = (const float*)d_in[2];
    const float* Wq   = (const float*)d_in[3];
    const float* Wk   = (const float*)d_in[4];
    const float* Wv   = (const float*)d_in[5];
    const float* Wp   = (const float*)d_in[6];
    const float* bp   = (const float*)d_in[7];
    const float* bias = (const float*)d_in[8];
    const int*   mask = (const int*)d_in[9];

    float* out  = (float*)d_out;               // (T,B,E) f32
    float* attn = out + (size_t)T_ * B_ * E_;  // (B,H,T,S) f32

    _Float16* qh   = (_Float16*)d_ws;          // (B,H,T,D)
    _Float16* kh   = qh + NH_;                 // (B,H,S,D)
    _Float16* vhT  = kh + NH_;                 // (B,H,D,S)
    _Float16* oh   = vhT + NH_;                // (T,B,E)
    _Float16* q16  = oh + NH_;                 // contiguous cvt_all dst
    _Float16* k16  = q16 + NH_;
    _Float16* v16  = k16 + NH_;
    _Float16* Wq16 = v16 + NH_;
    _Float16* Wk16 = Wq16 + EE_;
    _Float16* Wv16 = Wk16 + EE_;
    _Float16* Wp16 = Wv16 + EE_;

    dim3 blk(512);

    cvt_all<<<dim3(8192), dim3(256), 0, stream>>>(q, k, v, Wq, Wk, Wv, Wp, q16);

    qkv_gemm<<<dim3(32, 8, 3), blk, 0, stream>>>(
        q16, k16, v16, Wq16, Wk16, Wv16, qh, kh, vhT);

    fused_attn<<<dim3(4096), blk, 0, stream>>>(qh, kh, vhT, bias, mask, attn, oh);

    out_gemm<<<dim3(64, 8), blk, 0, stream>>>(oh, Wp16, bp, out);
}

// Round 19
// 253.260 us; speedup vs baseline: 1.0460x; 1.0460x over previous
//
#include <hip/hip_runtime.h>
#include <math.h>

// Problem constants
constexpr int T_ = 1024, S_ = 1024, B_ = 4, E_ = 1024, H_ = 16, D_ = 64;
constexpr float SCALE_ = 0.125f;                  // D^-0.5
constexpr size_t NH_ = (size_t)B_ * H_ * T_ * D_; // 4,194,304 elems
constexpr size_t EE_ = (size_t)E_ * E_;           // 1,048,576 elems

typedef _Float16 h8 __attribute__((ext_vector_type(8)));
typedef _Float16 h4 __attribute__((ext_vector_type(4)));
typedef float f4 __attribute__((ext_vector_type(4)));

__device__ inline f4 mfma16(h8 a, h8 b, f4 c) {
    return __builtin_amdgcn_mfma_f32_16x16x32_f16(a, b, c, 0, 0, 0);
}

// async global->LDS, 16B per lane; lds dest = wave-uniform base + lane*16
__device__ inline void gload_lds16(const void* g, void* l) {
    __builtin_amdgcn_global_load_lds(
        (const __attribute__((address_space(1))) void*)g,
        (__attribute__((address_space(3))) void*)l, 16, 0, 0);
}

// ---------------------------------------------------------------------------
// Fused f32 -> f16 converter for all 7 tensors (outputs contiguous in ws).
// ---------------------------------------------------------------------------
__global__ __launch_bounds__(256) void cvt_all(
    const float* __restrict__ q, const float* __restrict__ k,
    const float* __restrict__ v, const float* __restrict__ wq,
    const float* __restrict__ wk, const float* __restrict__ wv,
    const float* __restrict__ wp, _Float16* __restrict__ dst)
{
    const int i8 = blockIdx.x * 256 + threadIdx.x;   // 0 .. 2097151
    constexpr int BIG = (int)(NH_ / 8);              // 524288
    constexpr int WSZ = (int)(EE_ / 8);              // 131072
    const float* src;
    int loc;
    if (i8 < 3 * BIG) {
        int t = i8 / BIG; loc = i8 - t * BIG;
        src = t == 0 ? q : (t == 1 ? k : v);
    } else {
        int r = i8 - 3 * BIG;
        int t = r / WSZ; loc = r - t * WSZ;
        src = t == 0 ? wq : (t == 1 ? wk : (t == 2 ? wv : wp));
    }
    const float* p = src + (size_t)loc * 8;
    float4 a = *(const float4*)p;
    float4 b = *(const float4*)(p + 4);
    h8 o;
    o[0] = (_Float16)a.x; o[1] = (_Float16)a.y;
    o[2] = (_Float16)a.z; o[3] = (_Float16)a.w;
    o[4] = (_Float16)b.x; o[5] = (_Float16)b.y;
    o[6] = (_Float16)b.z; o[7] = (_Float16)b.w;
    *(h8*)&dst[(size_t)i8 * 8] = o;
}

// ---------------------------------------------------------------------------
// GEMM core 64x128 (out_gemm): BK=64, 512 thr = 8 waves (2x4), wave 32x32.
// ---------------------------------------------------------------------------
template <typename EPI>
__device__ inline void gemm_core(
    const _Float16* __restrict__ A, const _Float16* __restrict__ W,
    int m0, int n0, EPI epi)
{
    __shared__ _Float16 As[64][64];    //  8 KB linear
    __shared__ _Float16 Bs[128][64];   // 16 KB linear

    const int tid = threadIdx.x;
    const int w = tid >> 6, l = tid & 63, lr = l & 15, lg = l >> 4;
    const int wr = w >> 2, wc = w & 3;

    const int srow = (w << 3) + (l >> 3);       // 0..63 staged row
    const int sg   = (l & 7) ^ (srow & 7);      // swizzled source chunk
    char* AsB = (char*)As;
    char* BsB = (char*)Bs;
    char* ldsA  = AsB + w * 1024;
    char* ldsB0 = BsB + w * 1024;
    char* ldsB1 = BsB + 8192 + w * 1024;

    f4 acc[2][2];
#pragma unroll
    for (int mi = 0; mi < 2; ++mi)
#pragma unroll
        for (int ni = 0; ni < 2; ++ni) acc[mi][ni] = (f4){0.f, 0.f, 0.f, 0.f};

    for (int k0 = 0; k0 < 1024; k0 += 64) {
        gload_lds16(&A[(size_t)(m0 + srow) * 1024 + k0 + sg * 8], ldsA);
        gload_lds16(&W[(size_t)(n0 + srow) * 1024 + k0 + sg * 8], ldsB0);
        gload_lds16(&W[(size_t)(n0 + 64 + srow) * 1024 + k0 + sg * 8], ldsB1);
        __syncthreads();
#pragma unroll
        for (int kk = 0; kk < 2; ++kk) {
            h8 af[2], bf[2];
#pragma unroll
            for (int mi = 0; mi < 2; ++mi) {
                int r = wr * 32 + mi * 16 + lr, kc = kk * 4 + lg;
                af[mi] = *(const h8*)(AsB + r * 128 + ((kc ^ (r & 7)) << 4));
            }
#pragma unroll
            for (int ni = 0; ni < 2; ++ni) {
                int r = wc * 32 + ni * 16 + lr, kc = kk * 4 + lg;
                bf[ni] = *(const h8*)(BsB + r * 128 + ((kc ^ (r & 7)) << 4));
            }
#pragma unroll
            for (int mi = 0; mi < 2; ++mi)
#pragma unroll
                for (int ni = 0; ni < 2; ++ni)
                    acc[mi][ni] = mfma16(af[mi], bf[ni], acc[mi][ni]);
        }
        __syncthreads();
    }

#pragma unroll
    for (int mi = 0; mi < 2; ++mi)
#pragma unroll
        for (int ni = 0; ni < 2; ++ni)
#pragma unroll
            for (int r = 0; r < 4; ++r) {
                int row = m0 + wr * 32 + mi * 16 + lg * 4 + r;
                int col = n0 + wc * 32 + ni * 16 + lr;
                epi(row, col, acc[mi][ni][r]);
            }
}

// ---------------------------------------------------------------------------
// GEMM core 128x128 (qkv): BK=64, 512 thr = 8 waves (2x4), wave tile 64x32.
// ---------------------------------------------------------------------------
template <typename EPI>
__device__ inline void gemm_core128(
    const _Float16* __restrict__ A, const _Float16* __restrict__ W,
    int m0, int n0, EPI epi)
{
    __shared__ _Float16 As[128][64];   // 16 KB linear
    __shared__ _Float16 Bs[128][64];   // 16 KB linear

    const int tid = threadIdx.x;
    const int w = tid >> 6, l = tid & 63, lr = l & 15, lg = l >> 4;
    const int wr = w >> 2, wc = w & 3;

    char* AsB = (char*)As;
    char* BsB = (char*)Bs;

    f4 acc[4][2];
#pragma unroll
    for (int mi = 0; mi < 4; ++mi)
#pragma unroll
        for (int ni = 0; ni < 2; ++ni) acc[mi][ni] = (f4){0.f, 0.f, 0.f, 0.f};

    for (int k0 = 0; k0 < 1024; k0 += 64) {
#pragma unroll
        for (int d = 0; d < 2; ++d) {
            int row = w * 16 + d * 8 + (l >> 3);
            int sg = (l & 7) ^ (row & 7);
            gload_lds16(&A[(size_t)(m0 + row) * 1024 + k0 + sg * 8],
                        AsB + (w * 16 + d * 8) * 128);
            gload_lds16(&W[(size_t)(n0 + row) * 1024 + k0 + sg * 8],
                        BsB + (w * 16 + d * 8) * 128);
        }
        __syncthreads();
#pragma unroll
        for (int kk = 0; kk < 2; ++kk) {
            h8 af[4], bf[2];
#pragma unroll
            for (int mi = 0; mi < 4; ++mi) {
                int r = wr * 64 + mi * 16 + lr, kc = kk * 4 + lg;
                af[mi] = *(const h8*)(AsB + r * 128 + ((kc ^ (r & 7)) << 4));
            }
#pragma unroll
            for (int ni = 0; ni < 2; ++ni) {
                int r = wc * 32 + ni * 16 + lr, kc = kk * 4 + lg;
                bf[ni] = *(const h8*)(BsB + r * 128 + ((kc ^ (r & 7)) << 4));
            }
#pragma unroll
            for (int mi = 0; mi < 4; ++mi)
#pragma unroll
                for (int ni = 0; ni < 2; ++ni)
                    acc[mi][ni] = mfma16(af[mi], bf[ni], acc[mi][ni]);
        }
        __syncthreads();
    }

#pragma unroll
    for (int mi = 0; mi < 4; ++mi)
#pragma unroll
        for (int ni = 0; ni < 2; ++ni)
#pragma unroll
            for (int r = 0; r < 4; ++r) {
                int row = m0 + wr * 64 + mi * 16 + lg * 4 + r;
                int col = n0 + wc * 32 + ni * 16 + lr;
                epi(row, col, acc[mi][ni][r]);
            }
}

// ---------------------------------------------------------------------------
// Merged Q/K/V projection: blockIdx.z selects tensor. 128x128 tiles.
// ---------------------------------------------------------------------------
__global__ __launch_bounds__(512) void qkv_gemm(
    const _Float16* __restrict__ q16, const _Float16* __restrict__ k16,
    const _Float16* __restrict__ v16, const _Float16* __restrict__ Wq16,
    const _Float16* __restrict__ Wk16, const _Float16* __restrict__ Wv16,
    _Float16* __restrict__ qh, _Float16* __restrict__ kh,
    _Float16* __restrict__ vhT)
{
    const int z = blockIdx.z;
    const _Float16* A = z == 0 ? q16 : (z == 1 ? k16 : v16);
    const _Float16* W = z == 0 ? Wq16 : (z == 1 ? Wk16 : Wv16);
    _Float16* C = z == 0 ? qh : (z == 1 ? kh : vhT);
    const float scale = (z == 0) ? SCALE_ : 1.0f;
    const int m0 = blockIdx.x * 128, n0 = blockIdx.y * 128;

    if (z < 2) {
        gemm_core128(A, W, m0, n0, [&](int row, int col, float vv) {
            int t = row >> 2, b = row & 3, h = col >> 6, d = col & 63;
            C[(((size_t)b * H_ + h) * T_ + t) * D_ + d] = (_Float16)(vv * scale);
        });
    } else {
        gemm_core128(A, W, m0, n0, [&](int row, int col, float vv) {
            int s = row >> 2, b = row & 3, h = col >> 6, d = col & 63;
            C[(((size_t)b * H_ + h) * D_ + d) * S_ + s] = (_Float16)vv;
        });
    }
}

// ---------------------------------------------------------------------------
// Output projection: out = oh @ Wp^T + bp  (f32 out). 64x128 tiles.
// ---------------------------------------------------------------------------
__global__ __launch_bounds__(512) void out_gemm(
    const _Float16* __restrict__ oh, const _Float16* __restrict__ Wp16,
    const float* __restrict__ bp, float* __restrict__ out)
{
    const int m0 = blockIdx.x * 64, n0 = blockIdx.y * 128;
    gemm_core(oh, Wp16, m0, n0, [&](int row, int col, float vv) {
        out[(size_t)row * E_ + col] = vv + bp[col];
    });
}

// ---------------------------------------------------------------------------
// Fused attention (best-measured config, R17): per (bh, 16-row t-tile),
// 512 thr = 8 waves.
//   entry: issue 8x bias f4 (wave-private 16x16 tiles) + Q frags, pinned
//          with sched_barrier (T14).
//   ph1  : c = K.Q^T (swapped MFMA); bias^T via 4 lane-shuffles;
//          P = mask?0:exp(c+bias) -> swizzled LDS f16; rowsum in regs.
//   ph2  : inv = 1/sum(wsum); attn = P*inv nontemporal, coalesced.
//   ph3  : O = (P @ V)*inv, wave pairs split S, LDS reduce.
// Grid: 1D 4096, XCD-swizzled.
// ---------------------------------------------------------------------------
__global__ __launch_bounds__(512, 6) void fused_attn(
    const _Float16* __restrict__ qh, const _Float16* __restrict__ kh,
    const _Float16* __restrict__ vhT, const float* __restrict__ bias,
    const int* __restrict__ mask, float* __restrict__ attn,
    _Float16* __restrict__ oh)
{
    __shared__ _Float16 Pf[16 * 1024];   // swizzled, 32 KB
    __shared__ int aux_i[1024];          // mask (ph1) / PV partials (ph3)
    __shared__ float wsum[8][16];
    __shared__ float sinv16[16];
    char* Pb = (char*)Pf;

    const int bid = blockIdx.x;
    const int vid = (bid & 7) * 512 + (bid >> 3);   // 4096 % 8 == 0, bijective
    const int bh = vid >> 6;              // 0..63
    const int t0 = (vid & 63) * 16;       // 0..1008
    const int b = bh >> 4, h = bh & 15;
    const int tid = threadIdx.x;
    const int w = tid >> 6, l = tid & 63, lr = l & 15, lg = l >> 4;

    // ---- early issue: bias tiles (lane l: t=l>>2, s-quad=l&3) + Q frags ----
    const float* bbase = bias + ((size_t)bh * T_ + t0) * S_;
    const int brow_ = l >> 2, bq_ = l & 3;
    f4 bv[8];
#pragma unroll
    for (int j = 0; j < 8; ++j)
        bv[j] = *(const f4*)&bbase[(size_t)brow_ * S_ + w * 128 + j * 16 + bq_ * 4];

    const _Float16* qbase = qh + ((size_t)bh * T_ + t0) * D_;
    h8 qf0 = *(const h8*)&qbase[(size_t)lr * D_ + lg * 8];
    h8 qf1 = *(const h8*)&qbase[(size_t)lr * D_ + 32 + lg * 8];
    __builtin_amdgcn_sched_barrier(0);    // pin early issue

    for (int i = tid; i < S_; i += 512) aux_i[i] = mask[(size_t)b * S_ + i];
    __syncthreads();                      // mask staged

    const _Float16* kbase = kh + (size_t)bh * S_ * D_;
    const int wbase = w * 128;            // this wave's s-stripe
    const int srcLane = lr * 4 + lg;      // bias^T shuffle source

    // ---- phase 1: P = mask?0:exp(S+bias^T) -> LDS; rowsum in regs ----
    float rs = 0.f;
#pragma unroll
    for (int sub = 0; sub < 8; ++sub) {
        int s0 = wbase + sub * 16;
        h8 kf0 = *(const h8*)&kbase[(size_t)(s0 + lr) * D_ + lg * 8];
        h8 kf1 = *(const h8*)&kbase[(size_t)(s0 + lr) * D_ + 32 + lg * 8];
        f4 c = (f4){0.f, 0.f, 0.f, 0.f};
        c = mfma16(kf0, qf0, c);
        c = mfma16(kf1, qf1, c);
        float b0 = __shfl(bv[sub][0], srcLane);
        float b1 = __shfl(bv[sub][1], srcLane);
        float b2 = __shfl(bv[sub][2], srcLane);
        float b3 = __shfl(bv[sub][3], srcLane);
        int4 mv = *(const int4*)&aux_i[s0 + lg * 4];
        float p0 = mv.x ? 0.f : __expf(c[0] + b0);
        float p1 = mv.y ? 0.f : __expf(c[1] + b1);
        float p2 = mv.z ? 0.f : __expf(c[2] + b2);
        float p3 = mv.w ? 0.f : __expf(c[3] + b3);
        rs += (p0 + p1) + (p2 + p3);
        h4 pv;
        pv[0] = (_Float16)p0; pv[1] = (_Float16)p1;
        pv[2] = (_Float16)p2; pv[3] = (_Float16)p3;
        int off = (lr * 2048 + (s0 + lg * 4) * 2) ^ ((lr & 7) << 4);
        *(h4*)(Pb + off) = pv;
    }
    // wave rowsum for t=lr: sum the 4 lg groups
    rs += __shfl_xor(rs, 16); rs += __shfl_xor(rs, 32);
    if (l < 16) wsum[w][lr] = rs;
    __syncthreads();

    // ---- phase 2: inv; attn = P*inv (nontemporal, 4 rows x 512B/instr) ----
    {
        const int rr2 = tid >> 5;         // 0..15
        const int c2  = tid & 31;         // 0..31
        float s8 = 0.f;
#pragma unroll
        for (int ww = 0; ww < 8; ++ww) s8 += wsum[ww][rr2];   // broadcast reads
        float inv = 1.0f / s8;
        if (c2 == 0) sinv16[rr2] = inv;   // consumed in ph3 after its barrier
        float* arow = attn + ((size_t)bh * T_ + t0 + rr2) * S_;
#pragma unroll
        for (int j = 0; j < 8; ++j) {
            int col = c2 * 4 + j * 128;
            int off = (rr2 * 2048 + col * 2) ^ ((rr2 & 7) << 4);
            h4 p = *(const h4*)(Pb + off);
            f4 o = {(float)p[0] * inv, (float)p[1] * inv,
                    (float)p[2] * inv, (float)p[3] * inv};
            __builtin_nontemporal_store(o, (f4*)&arow[col]);
        }
    }

    // ---- phase 3: PV, wave pairs split S (512 each), LDS reduce ----
    {
        const int sh = w & 1, dbase = (w >> 1) * 16;
        const _Float16* vbase = vhT + (size_t)bh * D_ * S_;
        f4 acc = (f4){0.f, 0.f, 0.f, 0.f};
#pragma unroll 8
        for (int kc = 0; kc < 16; ++kc) {
            int s0 = sh * 512 + kc * 32;
            int off = (lr * 2048 + (s0 + lg * 8) * 2) ^ ((lr & 7) << 4);
            h8 pf = *(const h8*)(Pb + off);
            h8 vf = *(const h8*)&vbase[(size_t)(dbase + lr) * S_ + s0 + lg * 8];
            acc = mfma16(pf, vf, acc);
        }
        float* pvred = (float*)aux_i;     // mask no longer needed
        if (sh) {
#pragma unroll
            for (int r = 0; r < 4; ++r)
                pvred[(lg * 4 + r) * 64 + dbase + lr] = acc[r];
        }
        __syncthreads();
        if (!sh) {
#pragma unroll
            for (int r = 0; r < 4; ++r) {
                int t = lg * 4 + r;
                float o = (acc[r] + pvred[t * 64 + dbase + lr]) * sinv16[t];
                oh[((size_t)(t0 + t) * B_ + b) * E_ + h * 64 + dbase + lr] = (_Float16)o;
            }
        }
    }
}

// ---------------------------------------------------------------------------
extern "C" void kernel_launch(void* const* d_in, const int* in_sizes, int n_in,
                              void* d_out, int out_size, void* d_ws, size_t ws_size,
                              hipStream_t stream)
{
    const float* q    = (const float*)d_in[0];
    const float* k    = (const float*)d_in[1];
    const float* v    = (const float*)d_in[2];
    const float* Wq   = (const float*)d_in[3];
    const float* Wk   = (const float*)d_in[4];
    const float* Wv   = (const float*)d_in[5];
    const float* Wp   = (const float*)d_in[6];
    const float* bp   = (const float*)d_in[7];
    const float* bias = (const float*)d_in[8];
    const int*   mask = (const int*)d_in[9];

    float* out  = (float*)d_out;               // (T,B,E) f32
    float* attn = out + (size_t)T_ * B_ * E_;  // (B,H,T,S) f32

    _Float16* qh   = (_Float16*)d_ws;          // (B,H,T,D)
    _Float16* kh   = qh + NH_;                 // (B,H,S,D)
    _Float16* vhT  = kh + NH_;                 // (B,H,D,S)
    _Float16* oh   = vhT + NH_;                // (T,B,E)
    _Float16* q16  = oh + NH_;                 // contiguous cvt_all dst
    _Float16* k16  = q16 + NH_;
    _Float16* v16  = k16 + NH_;
    _Float16* Wq16 = v16 + NH_;
    _Float16* Wk16 = Wq16 + EE_;
    _Float16* Wv16 = Wk16 + EE_;
    _Float16* Wp16 = Wv16 + EE_;

    dim3 blk(512);

    cvt_all<<<dim3(8192), dim3(256), 0, stream>>>(q, k, v, Wq, Wk, Wv, Wp, q16);

    qkv_gemm<<<dim3(32, 8, 3), blk, 0, stream>>>(
        q16, k16, v16, Wq16, Wk16, Wv16, qh, kh, vhT);

    fused_attn<<<dim3(4096), blk, 0, stream>>>(qh, kh, vhT, bias, mask, attn, oh);

    out_gemm<<<dim3(64, 8), blk, 0, stream>>>(oh, Wp16, bp, out);
}